// Round 2
// baseline (6809.748 us; speedup 1.0000x reference)
//
#include <hip/hip_runtime.h>

// Problem constants (from reference setup_inputs / NUM_POINTS)
#define BATCH 16
#define NPTS  131072
#define NCH   6
#define KSEL  1024
#define MBLK  16                 // blocks per batch
#define TPB   256
#define CHUNK (NPTS / MBLK)      // 8192 points per block
#define PPT   (CHUNK / TPB)      // 32 points per thread
#define NWAVE (TPB / 64)         // 4
#define ROT   2                  // slot rotation depth (double buffer)
#define PLANE_OFF 4096           // byte offset of SoA planes in workspace
#define WS_NEED ((size_t)PLANE_OFF + 3ull * BATCH * NPTS * sizeof(float))

// pub[BATCH][ROT][MBLK] u64 (4 KB), memset 0 before launch.
// Word: [dist_f32_bits:32][~idx:20][tag:12], tag = round k (1..1023).
// All stores/loads RELAXED agent scope. u64 order: max dist first, then
// max ~idx = min global index — jnp.argmax first-occurrence tie-break.
// ROT=2 overwrite safety (causal): block A first overwrites slot (k&1) at
// round k+2, which requires A observed every block's round-(k+1) word.
//
// R14 post-mortem of R13: LDS residency REGRESSED (2630->3055). 96 scalar
// ds_read_b32/thread/round = ~2200 cyc/round LDS-pipe occupancy (m134:
// 5.8 cyc each) vs the L2 stream's ~1700 cyc (3 MB/round/XCD at ~1800
// B/cyc). FETCH_SIZE unchanged -> coords were already L2-resident. LDS is
// the WRONG tier for this shape; the lever is L2 BYTES, not tier.
//
// R14 = R12 skeleton + one-time SoA compaction in workspace:
//  - prepass copies xyz (AoS stride 24 B) into x/y/z planes (stride 4 B);
//    per-round L2 stream halves: 192 KB -> 96 KB per block (cache lines
//    fully used), and per-thread-contiguous ownership (thread t owns pts
//    [t*32,(t+1)*32)) turns 96 dword loads into 24 dwordx4.
//  - poll lanes prefetch their candidate's coords from the L2-resident
//    planes into LDS while polling; winner coords then come from LDS
//    (~120 cyc) instead of a serial ~250 cyc L2 fetch after the reduce.
//  - host falls back to the proven R12 path (COMPACT=0) if ws too small.
// R13 lesson kept: no bulk LDS coord residency. R5/R11: multi-word pub
// records banned; single-key publish only.

template <int COMPACT>
__global__ __launch_bounds__(TPB)
void fps_kernel(const float* __restrict__ pts, float* __restrict__ out,
                unsigned long long* __restrict__ pub)
{
#pragma clang fp contract(off)
    __shared__ float              s_wd[NWAVE];
    __shared__ int                s_wi[NWAVE];
    __shared__ unsigned long long s_key[MBLK];
    __shared__ float              s_cx[MBLK], s_cy[MBLK], s_cz[MBLK];

    const int b    = blockIdx.x % BATCH;     // batch-per-XCD swizzle
    const int m    = blockIdx.x / BATCH;
    const int tid  = threadIdx.x;
    const int base = m * CHUNK;
    const float* __restrict__ pb = pts + (size_t)b * NPTS * NCH;

    float* __restrict__ xp = (float*)((char*)pub + PLANE_OFF) + (size_t)b * NPTS;
    float* __restrict__ yp = xp + (size_t)BATCH * NPTS;
    float* __restrict__ zp = yp + (size_t)BATCH * NPTS;

    float dmin[PPT];
#pragma unroll
    for (int i = 0; i < PPT; ++i) dmin[i] = __builtin_inff();

    // R12-path staging registers (only used when COMPACT==0)
    float xr[PPT], yr[PPT], zr[PPT];

    if (COMPACT) {
        // prepass: compact own chunk AoS xyz -> SoA planes (coalesced both
        // sides). Written interleaved (j = tid + i*TPB), read back
        // per-thread-contiguous -> needs fence + barrier for cross-lane
        // visibility through L2. One-time cost.
#pragma unroll
        for (int i = 0; i < PPT; ++i) {
            const int j = base + tid + i * TPB;
            const float* p = pb + (size_t)j * NCH;
            xp[j] = p[0]; yp[j] = p[1]; zp[j] = p[2];
        }
    } else {
#pragma unroll
        for (int i = 0; i < PPT; ++i) {
            const float* p = pb + (size_t)(base + tid + i * TPB) * NCH;
            xr[i] = p[0]; yr[i] = p[1]; zr[i] = p[2];
        }
    }

    // Selected index 0 -> output row 0.
    if (m == 0 && tid < NCH) out[(size_t)b * KSEL * NCH + tid] = pb[tid];

    if (COMPACT) { __threadfence(); }
    __syncthreads();

    const float4* __restrict__ xv = (const float4*)(xp + base + tid * PPT);
    const float4* __restrict__ yv = (const float4*)(yp + base + tid * PPT);
    const float4* __restrict__ zv = (const float4*)(zp + base + tid * PPT);

    // p for round 1 is point 0 (uniform scalar loads of read-only data).
    float px = pb[0], py = pb[1], pz = pb[2];

    for (int k = 1; k < KSEL; ++k) {
        // ---- dist update + thread-local argmax (first-index tie-break) ----
        // Bit-exact replication of the reference's f32 op sequence: each op
        // individually rounded (RN), no FMA / no reassociation.
        float bd = -1.0f;
        int   bj = 0;
        if (COMPACT) {
#pragma unroll
            for (int u = 0; u < PPT / 4; ++u) {
                const float4 X = xv[u], Y = yv[u], Z = zv[u];
#define FPS_DO(c, comp)                                                      \
                {                                                            \
                    float dx = __fsub_rn(X.comp, px);                        \
                    float dy = __fsub_rn(Y.comp, py);                        \
                    float dz = __fsub_rn(Z.comp, pz);                        \
                    float d  = __fadd_rn(__fadd_rn(__fmul_rn(dx, dx),        \
                                                   __fmul_rn(dy, dy)),       \
                                         __fmul_rn(dz, dz));                 \
                    const int i = u * 4 + (c);                               \
                    float dm = dmin[i];                                      \
                    dm = (d < dm) ? d : dm;                                  \
                    dmin[i] = dm;                                            \
                    /* in-chunk j = tid*PPT + i ascends with i: '>' keeps */ \
                    /* first index */                                        \
                    if (dm > bd) { bd = dm; bj = tid * PPT + i; }            \
                }
                FPS_DO(0, x) FPS_DO(1, y) FPS_DO(2, z) FPS_DO(3, w)
#undef FPS_DO
            }
        } else {
#pragma unroll
            for (int i = 0; i < PPT; ++i) {
                float dx = __fsub_rn(xr[i], px);
                float dy = __fsub_rn(yr[i], py);
                float dz = __fsub_rn(zr[i], pz);
                float d  = __fadd_rn(__fadd_rn(__fmul_rn(dx, dx),
                                               __fmul_rn(dy, dy)),
                                     __fmul_rn(dz, dz));
                float dm = dmin[i];
                dm = (d < dm) ? d : dm;
                dmin[i] = dm;
                if (dm > bd) { bd = dm; bj = tid + i * TPB; }
            }
        }

        // ---- wave(64) argmax reduce, smaller index wins ties ----
        for (int off = 32; off > 0; off >>= 1) {
            float od = __shfl_down(bd, off);
            int   oj = __shfl_down(bj, off);
            if (od > bd || (od == bd && oj < bj)) { bd = od; bj = oj; }
        }
        if ((tid & 63) == 0) {
            const int w = tid >> 6;
            s_wd[w] = bd; s_wi[w] = bj;
        }
        __syncthreads();                                   // [A]

        unsigned long long* slot =
            pub + ((size_t)b * ROT + (size_t)(k & (ROT - 1))) * MBLK;

        // ---- publish this block's tagged key (tid 0) ----
        if (tid == 0) {
            float fd = s_wd[0]; int fi = s_wi[0];
#pragma unroll
            for (int w = 1; w < NWAVE; ++w) {
                if (s_wd[w] > fd || (s_wd[w] == fd && s_wi[w] < fi)) {
                    fd = s_wd[w]; fi = s_wi[w];
                }
            }
            const unsigned g   = (unsigned)(base + fi);
            const unsigned inv = 0xFFFFFu ^ g;             // 20-bit ~idx
            unsigned long long key =
                ((unsigned long long)__float_as_uint(fd) << 32)
                | ((unsigned long long)inv << 12)
                | (unsigned long long)(unsigned)k;         // 12-bit tag
            __hip_atomic_store(&slot[m], key, __ATOMIC_RELAXED,
                               __HIP_MEMORY_SCOPE_AGENT);
        }

        // ---- parallel poll: lane j waits for block j's word ----
        if (tid < MBLK) {
            unsigned long long v;
            do {
                v = __hip_atomic_load(&slot[tid], __ATOMIC_RELAXED,
                                      __HIP_MEMORY_SCOPE_AGENT);
            } while ((unsigned)(v & 0xFFFull) != (unsigned)k);
            s_key[tid] = v;
            // Candidate-coord prefetch: only the winner's is used, but all
            // 16 land in LDS before [B]; winner read becomes LDS-latency.
            const unsigned gw =
                0xFFFFFu ^ (unsigned)((v >> 12) & 0xFFFFFull);
            if (COMPACT) {
                s_cx[tid] = xp[gw]; s_cy[tid] = yp[gw]; s_cz[tid] = zp[gw];
            } else {
                const float* cp = pb + (size_t)gw * NCH;
                s_cx[tid] = cp[0]; s_cy[tid] = cp[1]; s_cz[tid] = cp[2];
            }
        }
        __syncthreads();                                   // [B]

        // ---- every thread: reduce 16 keys, winner coords from LDS ----
        // s_key/s_c* reads precede next round's [A]; the poll rewrites them
        // only after [A] -> no race without a third barrier.
        unsigned long long mx = s_key[0]; int wsl = 0;
#pragma unroll
        for (int w = 1; w < MBLK; ++w) {
            if (s_key[w] > mx) { mx = s_key[w]; wsl = w; }
        }
        px = s_cx[wsl]; py = s_cy[wsl]; pz = s_cz[wsl];

        // Round-robin writer block emits output row k (all 6 channels from
        // AoS; once per 16 rounds per block, off the common critical path).
        if ((k & (MBLK - 1)) == m && tid == 0) {
            const unsigned g =
                0xFFFFFu ^ (unsigned)((mx >> 12) & 0xFFFFFull);
            const float* pp = pb + (size_t)g * NCH;
            float* o = out + ((size_t)b * KSEL + k) * NCH;
#pragma unroll
            for (int c = 0; c < NCH; ++c) o[c] = pp[c];
        }
    }
}

extern "C" void kernel_launch(void* const* d_in, const int* in_sizes, int n_in,
                              void* d_out, int out_size, void* d_ws, size_t ws_size,
                              hipStream_t stream) {
    const float* pts = (const float*)d_in[0];
    float* out = (float*)d_out;
    unsigned long long* pub = (unsigned long long*)d_ws;

    // pub[BATCH][ROT][MBLK] u64 = 4 KB; zero -> all tags 0 (never match).
    hipMemsetAsync(d_ws, 0,
                   (size_t)BATCH * ROT * MBLK * sizeof(unsigned long long),
                   stream);

    void* args[] = { (void*)&pts, (void*)&out, (void*)&pub };
    const void* fn = (ws_size >= WS_NEED)
        ? (const void*)fps_kernel<1>
        : (const void*)fps_kernel<0>;   // R12 fallback if ws too small
    hipLaunchCooperativeKernel(fn, dim3(BATCH * MBLK), dim3(TPB),
                               args, 0, stream);
}

// Round 3
// 4746.164 us; speedup vs baseline: 1.4348x; 1.4348x over previous
//
#include <hip/hip_runtime.h>

// Problem constants (from reference setup_inputs / NUM_POINTS)
#define BATCH 16
#define NPTS  131072
#define NCH   6
#define KSEL  1024
#define MBLK  16                 // blocks per batch
#define TPB   256
#define CHUNK (NPTS / MBLK)      // 8192 points per block
#define PPT   (CHUNK / TPB)      // 32 points per thread
#define NVEC  (PPT / 4)          // 8 float4 groups per thread
#define NWAVE (TPB / 64)         // 4
#define ROT   2                  // slot rotation depth (double buffer)
#define PLANE_OFF 4096           // byte offset of SoA planes in workspace
#define WS_NEED ((size_t)PLANE_OFF + 3ull * BATCH * NPTS * sizeof(float))

// pub[BATCH][ROT][MBLK] u64 (4 KB), memset 0 before launch.
// Word: [dist_f32_bits:32][~idx:20][tag:12], tag = round k (1..1023).
// All stores/loads RELAXED agent scope. u64 order: max dist first, then
// max ~idx = min global index — jnp.argmax first-occurrence tie-break.
// ROT=2 overwrite safety (causal): block A first overwrites slot (k&1) at
// round k+2, which requires A observed every block's round-(k+1) word.
//
// R15 post-mortem chain:
//  R13: bulk LDS residency -> REGRESSED (scalar ds_read pipe narrower
//       than XCD-L2 for this shape).
//  R14: SoA planes + PER-THREAD-CONTIGUOUS float4 reads -> 2.7x REGRESSION.
//       Lane stride 128 B means every dwordx4 touches 64 distinct cache
//       lines; L1/TA processes line requests serially (~64/instr vs ~8
//       coalesced). VALUBusy collapsed to 8.9%. Lesson: per-wave-instr
//       LINE COUNT is the cost metric, not bytes.
//  R15 = SoA planes kept, reads WAVE-COALESCED float4: vector group
//       v = u*TPB + tid, thread loads plane[base + 4*v .. +3]. Lane
//       stride 16 B -> 1024 B contiguous per wave instr (8 lines), 24
//       dwordx4/thread/round vs R12's 96 dword. Bytes halved vs R12 AND
//       minimal divergence. In-chunk index 4*(u*TPB+tid)+c ascends in
//       scan order -> first-occurrence tie-break preserved.
// R5/R11: multi-word pub records banned; single-key publish only.

template <int COMPACT>
__global__ __launch_bounds__(TPB)
void fps_kernel(const float* __restrict__ pts, float* __restrict__ out,
                unsigned long long* __restrict__ pub)
{
#pragma clang fp contract(off)
    __shared__ float              s_wd[NWAVE];
    __shared__ int                s_wi[NWAVE];
    __shared__ unsigned long long s_key[MBLK];
    __shared__ float              s_cx[MBLK], s_cy[MBLK], s_cz[MBLK];

    const int b    = blockIdx.x % BATCH;     // batch-per-XCD swizzle
    const int m    = blockIdx.x / BATCH;
    const int tid  = threadIdx.x;
    const int base = m * CHUNK;
    const float* __restrict__ pb = pts + (size_t)b * NPTS * NCH;

    float* __restrict__ xp = (float*)((char*)pub + PLANE_OFF) + (size_t)b * NPTS;
    float* __restrict__ yp = xp + (size_t)BATCH * NPTS;
    float* __restrict__ zp = yp + (size_t)BATCH * NPTS;

    float dmin[PPT];
#pragma unroll
    for (int i = 0; i < PPT; ++i) dmin[i] = __builtin_inff();

    // R12-path staging registers (only used when COMPACT==0)
    float xr[PPT], yr[PPT], zr[PPT];

    if (COMPACT) {
        // prepass: compact own chunk AoS xyz -> SoA planes (coalesced both
        // sides). Cross-thread read-back -> fence + barrier. One-time.
#pragma unroll
        for (int i = 0; i < PPT; ++i) {
            const int j = base + tid + i * TPB;
            const float* p = pb + (size_t)j * NCH;
            xp[j] = p[0]; yp[j] = p[1]; zp[j] = p[2];
        }
    } else {
#pragma unroll
        for (int i = 0; i < PPT; ++i) {
            const float* p = pb + (size_t)(base + tid + i * TPB) * NCH;
            xr[i] = p[0]; yr[i] = p[1]; zr[i] = p[2];
        }
    }

    // Selected index 0 -> output row 0.
    if (m == 0 && tid < NCH) out[(size_t)b * KSEL * NCH + tid] = pb[tid];

    if (COMPACT) { __threadfence(); }
    __syncthreads();

    // Wave-coalesced vector view: thread handles float4 group v = u*TPB+tid,
    // i.e. points 4v..4v+3 (lane stride 16 B -> 1024 B/wave instr).
    const float4* __restrict__ xv = (const float4*)(xp + base);
    const float4* __restrict__ yv = (const float4*)(yp + base);
    const float4* __restrict__ zv = (const float4*)(zp + base);

    // p for round 1 is point 0 (uniform scalar loads of read-only data).
    float px = pb[0], py = pb[1], pz = pb[2];

    for (int k = 1; k < KSEL; ++k) {
        // ---- dist update + thread-local argmax (first-index tie-break) ----
        // Bit-exact replication of the reference's f32 op sequence: each op
        // individually rounded (RN), no FMA / no reassociation.
        float bd = -1.0f;
        int   bj = 0;
        if (COMPACT) {
#pragma unroll
            for (int u = 0; u < NVEC; ++u) {
                const int v = u * TPB + tid;
                const float4 X = xv[v], Y = yv[v], Z = zv[v];
#define FPS_DO(c, comp)                                                      \
                {                                                            \
                    float dx = __fsub_rn(X.comp, px);                        \
                    float dy = __fsub_rn(Y.comp, py);                        \
                    float dz = __fsub_rn(Z.comp, pz);                        \
                    float d  = __fadd_rn(__fadd_rn(__fmul_rn(dx, dx),        \
                                                   __fmul_rn(dy, dy)),       \
                                         __fmul_rn(dz, dz));                 \
                    const int i = u * 4 + (c);                               \
                    float dm = dmin[i];                                      \
                    dm = (d < dm) ? d : dm;                                  \
                    dmin[i] = dm;                                            \
                    /* in-chunk j = 4v+c ascends over (u,c) scan order:  */ \
                    /* strict '>' keeps first (smallest) index           */ \
                    if (dm > bd) { bd = dm; bj = 4 * v + (c); }              \
                }
                FPS_DO(0, x) FPS_DO(1, y) FPS_DO(2, z) FPS_DO(3, w)
#undef FPS_DO
            }
        } else {
#pragma unroll
            for (int i = 0; i < PPT; ++i) {
                float dx = __fsub_rn(xr[i], px);
                float dy = __fsub_rn(yr[i], py);
                float dz = __fsub_rn(zr[i], pz);
                float d  = __fadd_rn(__fadd_rn(__fmul_rn(dx, dx),
                                               __fmul_rn(dy, dy)),
                                     __fmul_rn(dz, dz));
                float dm = dmin[i];
                dm = (d < dm) ? d : dm;
                dmin[i] = dm;
                if (dm > bd) { bd = dm; bj = tid + i * TPB; }
            }
        }

        // ---- wave(64) argmax reduce, smaller index wins ties ----
        for (int off = 32; off > 0; off >>= 1) {
            float od = __shfl_down(bd, off);
            int   oj = __shfl_down(bj, off);
            if (od > bd || (od == bd && oj < bj)) { bd = od; bj = oj; }
        }
        if ((tid & 63) == 0) {
            const int w = tid >> 6;
            s_wd[w] = bd; s_wi[w] = bj;
        }
        __syncthreads();                                   // [A]

        unsigned long long* slot =
            pub + ((size_t)b * ROT + (size_t)(k & (ROT - 1))) * MBLK;

        // ---- publish this block's tagged key (tid 0) ----
        if (tid == 0) {
            float fd = s_wd[0]; int fi = s_wi[0];
#pragma unroll
            for (int w = 1; w < NWAVE; ++w) {
                if (s_wd[w] > fd || (s_wd[w] == fd && s_wi[w] < fi)) {
                    fd = s_wd[w]; fi = s_wi[w];
                }
            }
            const unsigned g   = (unsigned)(base + fi);
            const unsigned inv = 0xFFFFFu ^ g;             // 20-bit ~idx
            unsigned long long key =
                ((unsigned long long)__float_as_uint(fd) << 32)
                | ((unsigned long long)inv << 12)
                | (unsigned long long)(unsigned)k;         // 12-bit tag
            __hip_atomic_store(&slot[m], key, __ATOMIC_RELAXED,
                               __HIP_MEMORY_SCOPE_AGENT);
        }

        // ---- parallel poll: lane j waits for block j's word ----
        if (tid < MBLK) {
            unsigned long long v;
            do {
                v = __hip_atomic_load(&slot[tid], __ATOMIC_RELAXED,
                                      __HIP_MEMORY_SCOPE_AGENT);
            } while ((unsigned)(v & 0xFFFull) != (unsigned)k);
            s_key[tid] = v;
            // Candidate-coord prefetch: all 16 land in LDS before [B];
            // winner read after the reduce becomes LDS-latency.
            const unsigned gw =
                0xFFFFFu ^ (unsigned)((v >> 12) & 0xFFFFFull);
            if (COMPACT) {
                s_cx[tid] = xp[gw]; s_cy[tid] = yp[gw]; s_cz[tid] = zp[gw];
            } else {
                const float* cp = pb + (size_t)gw * NCH;
                s_cx[tid] = cp[0]; s_cy[tid] = cp[1]; s_cz[tid] = cp[2];
            }
        }
        __syncthreads();                                   // [B]

        // ---- every thread: reduce 16 keys, winner coords from LDS ----
        // s_key/s_c* reads precede next round's [A]; the poll rewrites them
        // only after [A] -> no race without a third barrier.
        unsigned long long mx = s_key[0]; int wsl = 0;
#pragma unroll
        for (int w = 1; w < MBLK; ++w) {
            if (s_key[w] > mx) { mx = s_key[w]; wsl = w; }
        }
        px = s_cx[wsl]; py = s_cy[wsl]; pz = s_cz[wsl];

        // Round-robin writer block emits output row k (all 6 channels from
        // AoS; once per 16 rounds per block, off the critical path).
        if ((k & (MBLK - 1)) == m && tid == 0) {
            const unsigned g =
                0xFFFFFu ^ (unsigned)((mx >> 12) & 0xFFFFFull);
            const float* pp = pb + (size_t)g * NCH;
            float* o = out + ((size_t)b * KSEL + k) * NCH;
#pragma unroll
            for (int c = 0; c < NCH; ++c) o[c] = pp[c];
        }
    }
}

extern "C" void kernel_launch(void* const* d_in, const int* in_sizes, int n_in,
                              void* d_out, int out_size, void* d_ws, size_t ws_size,
                              hipStream_t stream) {
    const float* pts = (const float*)d_in[0];
    float* out = (float*)d_out;
    unsigned long long* pub = (unsigned long long*)d_ws;

    // pub[BATCH][ROT][MBLK] u64 = 4 KB; zero -> all tags 0 (never match).
    hipMemsetAsync(d_ws, 0,
                   (size_t)BATCH * ROT * MBLK * sizeof(unsigned long long),
                   stream);

    void* args[] = { (void*)&pts, (void*)&out, (void*)&pub };
    const void* fn = (ws_size >= WS_NEED)
        ? (const void*)fps_kernel<1>
        : (const void*)fps_kernel<0>;   // R12 fallback if ws too small
    hipLaunchCooperativeKernel(fn, dim3(BATCH * MBLK), dim3(TPB),
                               args, 0, stream);
}

// Round 4
// 2975.938 us; speedup vs baseline: 2.2883x; 1.5948x over previous
//
#include <hip/hip_runtime.h>

// Problem constants (from reference setup_inputs / NUM_POINTS)
#define BATCH 16
#define NPTS  131072
#define NCH   6
#define KSEL  1024
#define MBLK  16                 // blocks per batch
#define TPB   256
#define CHUNK (NPTS / MBLK)      // 8192 points per block
#define PPT   (CHUNK / TPB)      // 32 points per thread
#define NWAVE (TPB / 64)         // 4
#define ROT   2                  // slot rotation depth (double buffer)

// pub[BATCH][ROT][MBLK] u64 (4 KB), memset 0 before launch.
// Word: [dist_f32_bits:32][~idx:20][tag:12], tag = round k (1..1023).
// All stores/loads RELAXED agent scope. u64 order: max dist first, then
// max ~idx = min global index — jnp.argmax first-occurrence tie-break.
// ROT=2 overwrite safety (causal): block A first overwrites slot (k&1) at
// round k+2, which requires A observed every block's round-(k+1) word.
//
// R16 theory. R13 (LDS tier), R14 (SoA + divergent f4), R15 (SoA +
// coalesced f4) all regressed vs R12's L2 stream — R15's failure was
// latency serialization (VGPR=68 -> ~8 serial L2 round-trips/round).
// Meta-lesson: the k-loop re-reads an INVARIANT 96 KB working set 1023
// times; every memory tier charges per-round rent. The only free tier is
// the register file, and we have 512 VGPR/wave available (grid = 1
// block/CU -> 1 wave/SIMD) while using 96.
//   - __launch_bounds__(TPB, 1): 2nd arg = min waves per EU -> VGPR
//     budget 512. The earlier session's "register residency = spills at
//     VGPR 96" (R8-R10) is explained by the missing occupancy declaration.
//   - one-time asm "+v" pins after the fill make xr/yr/zr opaque: the
//     compiler cannot remat the loads into the k-loop (R12's behavior)
//     and has no pressure reason to spill. 128 data VGPRs, all indices
//     compile-time (rule #20: no runtime indexing -> no scratch).
//   - k-loop touches NO memory for coords: ~770 cyc VALU + ~240 reduce +
//     ~1300 sync ≈ 2400 cyc/round vs R12's 6170.
// Poll-window winner-coord LDS prefetch (R14) kept: overlaps the serial
// post-reduce L2 read with the poll. R5/R11: multi-word pub records
// banned; single-key publish only.

extern "C" __global__ __launch_bounds__(TPB, 1)
void fps_kernel(const float* __restrict__ pts, float* __restrict__ out,
                unsigned long long* __restrict__ pub)
{
#pragma clang fp contract(off)
    __shared__ float              s_wd[NWAVE];
    __shared__ int                s_wi[NWAVE];
    __shared__ unsigned long long s_key[MBLK];
    __shared__ float              s_cx[MBLK], s_cy[MBLK], s_cz[MBLK];

    const int b    = blockIdx.x % BATCH;     // batch-per-XCD swizzle
    const int m    = blockIdx.x / BATCH;
    const int tid  = threadIdx.x;
    const int base = m * CHUNK;
    const float* __restrict__ pb = pts + (size_t)b * NPTS * NCH;

    // One-time fill: coords live in VGPRs for the whole kernel.
    float xr[PPT], yr[PPT], zr[PPT], dmin[PPT];
#pragma unroll
    for (int i = 0; i < PPT; ++i) {
        const float* p = pb + (size_t)(base + tid + i * TPB) * NCH;
        xr[i]   = p[0];
        yr[i]   = p[1];
        zr[i]   = p[2];
        dmin[i] = __builtin_inff();
    }
    // Anti-remat pin: values become opaque -> must stay in registers.
#pragma unroll
    for (int i = 0; i < PPT; ++i) {
        asm volatile("" : "+v"(xr[i]), "+v"(yr[i]), "+v"(zr[i]));
    }

    // Selected index 0 -> output row 0.
    if (m == 0 && tid < NCH) out[(size_t)b * KSEL * NCH + tid] = pb[tid];

    // p for round 1 is point 0 (uniform scalar loads of read-only data).
    float px = pb[0], py = pb[1], pz = pb[2];

    for (int k = 1; k < KSEL; ++k) {
        // ---- dist update + thread-local argmax (first-index tie-break) ----
        float bd = -1.0f;
        int   bj = 0;
#pragma unroll
        for (int i = 0; i < PPT; ++i) {
            // Bit-exact replication of the reference's f32 op sequence:
            // each op individually rounded (RN), no FMA / no reassociation.
            float dx = __fsub_rn(xr[i], px);
            float dy = __fsub_rn(yr[i], py);
            float dz = __fsub_rn(zr[i], pz);
            float d  = __fadd_rn(__fadd_rn(__fmul_rn(dx, dx),
                                           __fmul_rn(dy, dy)),
                                 __fmul_rn(dz, dz));
            float dm = dmin[i];
            dm = (d < dm) ? d : dm;
            dmin[i] = dm;
            // j = tid + i*TPB ascends with i: strict '>' keeps first index.
            if (dm > bd) { bd = dm; bj = tid + i * TPB; }
        }

        // ---- wave(64) argmax reduce, smaller index wins ties ----
        for (int off = 32; off > 0; off >>= 1) {
            float od = __shfl_down(bd, off);
            int   oj = __shfl_down(bj, off);
            if (od > bd || (od == bd && oj < bj)) { bd = od; bj = oj; }
        }
        if ((tid & 63) == 0) {
            const int w = tid >> 6;
            s_wd[w] = bd; s_wi[w] = bj;
        }
        __syncthreads();                                   // [A]

        unsigned long long* slot =
            pub + ((size_t)b * ROT + (size_t)(k & (ROT - 1))) * MBLK;

        // ---- publish this block's tagged key (tid 0) ----
        if (tid == 0) {
            float fd = s_wd[0]; int fi = s_wi[0];
#pragma unroll
            for (int w = 1; w < NWAVE; ++w) {
                if (s_wd[w] > fd || (s_wd[w] == fd && s_wi[w] < fi)) {
                    fd = s_wd[w]; fi = s_wi[w];
                }
            }
            const unsigned g   = (unsigned)(base + fi);
            const unsigned inv = 0xFFFFFu ^ g;             // 20-bit ~idx
            unsigned long long key =
                ((unsigned long long)__float_as_uint(fd) << 32)
                | ((unsigned long long)inv << 12)
                | (unsigned long long)(unsigned)k;         // 12-bit tag
            __hip_atomic_store(&slot[m], key, __ATOMIC_RELAXED,
                               __HIP_MEMORY_SCOPE_AGENT);
        }

        // ---- parallel poll: lane j waits for block j's word ----
        if (tid < MBLK) {
            unsigned long long v;
            do {
                v = __hip_atomic_load(&slot[tid], __ATOMIC_RELAXED,
                                      __HIP_MEMORY_SCOPE_AGENT);
            } while ((unsigned)(v & 0xFFFull) != (unsigned)k);
            s_key[tid] = v;
            // Candidate-coord prefetch: all 16 land in LDS before [B];
            // the post-reduce winner read becomes LDS-latency.
            const unsigned gw =
                0xFFFFFu ^ (unsigned)((v >> 12) & 0xFFFFFull);
            const float* cp = pb + (size_t)gw * NCH;
            s_cx[tid] = cp[0]; s_cy[tid] = cp[1]; s_cz[tid] = cp[2];
        }
        __syncthreads();                                   // [B]

        // ---- every thread: reduce 16 keys, winner coords from LDS ----
        // s_key/s_c* reads precede next round's [A]; the poll rewrites
        // them only after [A] -> no race without a third barrier.
        unsigned long long mx = s_key[0]; int wsl = 0;
#pragma unroll
        for (int w = 1; w < MBLK; ++w) {
            if (s_key[w] > mx) { mx = s_key[w]; wsl = w; }
        }
        px = s_cx[wsl]; py = s_cy[wsl]; pz = s_cz[wsl];

        // Round-robin writer block emits output row k (all 6 channels
        // from AoS; once per 16 rounds per block, off the critical path).
        if ((k & (MBLK - 1)) == m && tid == 0) {
            const unsigned g =
                0xFFFFFu ^ (unsigned)((mx >> 12) & 0xFFFFFull);
            const float* pp = pb + (size_t)g * NCH;
            float* o = out + ((size_t)b * KSEL + k) * NCH;
#pragma unroll
            for (int c = 0; c < NCH; ++c) o[c] = pp[c];
        }
    }
}

extern "C" void kernel_launch(void* const* d_in, const int* in_sizes, int n_in,
                              void* d_out, int out_size, void* d_ws, size_t ws_size,
                              hipStream_t stream) {
    const float* pts = (const float*)d_in[0];
    float* out = (float*)d_out;
    unsigned long long* pub = (unsigned long long*)d_ws;

    // pub[BATCH][ROT][MBLK] u64 = 4 KB; zero -> all tags 0 (never match).
    hipMemsetAsync(d_ws, 0,
                   (size_t)BATCH * ROT * MBLK * sizeof(unsigned long long),
                   stream);

    void* args[] = { (void*)&pts, (void*)&out, (void*)&pub };
    hipLaunchCooperativeKernel((const void*)fps_kernel,
                               dim3(BATCH * MBLK), dim3(TPB),
                               args, 0, stream);
}

// Round 8
// 2743.048 us; speedup vs baseline: 2.4825x; 1.0849x over previous
//
#include <hip/hip_runtime.h>

// Problem constants (from reference setup_inputs / NUM_POINTS)
#define BATCH 16
#define NPTS  131072
#define NCH   6
#define KSEL  1024
#define MBLK  16                 // blocks per batch
#define TPB   256                // proven geometry (512 kills the harness)
#define CHUNK (NPTS / MBLK)      // 8192 points per block
#define PPT   (CHUNK / TPB)      // 32 points per thread
#define NWAVE (TPB / 64)         // 4
#define ROT   2                  // slot rotation depth (double buffer)
#define PLANE_OFF 4096           // byte offset of SoA planes in workspace
#define WS_NEED ((size_t)PLANE_OFF + 3ull * BATCH * NPTS * sizeof(float))

// pub[BATCH][ROT][MBLK] u64 (4 KB), memset 0 before launch.
// Word: [dist_f32_bits:32][~idx:20][tag:12], tag = round k (1..1023).
// All stores/loads RELAXED agent scope. u64 order: max dist first, then
// max ~idx = min global index — jnp.argmax first-occurrence tie-break.
// ROT=2 overwrite safety (causal): block A first overwrites slot (k&1) at
// round k+2, which requires A observed every block's round-(k+1) word.
//
// R20. Revised budget for R12's 6170-cyc round: XCD-L2 STREAM ~3000 cyc
// (32 blocks/XCD x 192 KB AoS line footprint / ~2KB/cyc), VALU ~1400
// (22.9% VALUBusy), sync ~1500. The stream is the dominant term; prior
// tier experiments failed mechanically, not conceptually:
//   R13 LDS: scalar ds_read pipe (2200 cyc) > L2 stream. R14 SoA
//   thread-contiguous: 64 lines/wave-instr TA overload. R15 SoA float4
//   regrouped: issue serialization at VGPR=68 (vmcnt(0) every ~3 loads).
//   R16 register pin: allocator wall ~96 regs -> scratch. R19 bundled
//   wave-publish + prefetch -> WRONG RESULTS (absmax 5.4, unlocalized;
//   both pieces banned pending bisect).
// R20 = R12 EXACT skeleton; only the k-loop load TARGET changes: one-time
// SoA compaction (xyz planes in ws), k-loop reads planes with R12's SAME
// j = tid + i*TPB mapping and scalar loads. Lane stride 4 B -> 4
// lines/wave-instr (vs 24 AoS), bytes halve (96 KB/block/round). Planes
// are written & read by the SAME thread at the SAME addresses -> no
// cross-thread visibility needed; __syncthreads (vmcnt drain) orders
// prepass stores before k-loop loads. Tie-break indices unchanged.
// Host falls back to exact-R12 (COMPACT=0) if ws too small.

template <int COMPACT>
__global__ __launch_bounds__(TPB)
void fps_kernel(const float* __restrict__ pts, float* __restrict__ out,
                unsigned long long* __restrict__ pub)
{
#pragma clang fp contract(off)
    __shared__ float              s_wd[NWAVE];
    __shared__ int                s_wi[NWAVE];
    __shared__ unsigned long long s_key[MBLK];

    const int b    = blockIdx.x % BATCH;     // batch-per-XCD swizzle
    const int m    = blockIdx.x / BATCH;
    const int tid  = threadIdx.x;
    const int base = m * CHUNK;
    const float* __restrict__ pb = pts + (size_t)b * NPTS * NCH;

    float* __restrict__ xp = (float*)((char*)pub + PLANE_OFF) + (size_t)b * NPTS;
    float* __restrict__ yp = xp + (size_t)BATCH * NPTS;
    float* __restrict__ zp = yp + (size_t)BATCH * NPTS;

    if (COMPACT) {
        // One-time compaction: own chunk AoS xyz -> SoA planes. Write
        // lane stride 4 B (coalesced); read side below uses the SAME
        // thread & addresses -> no cross-thread visibility needed.
#pragma unroll
        for (int i = 0; i < PPT; ++i) {
            const int j = base + tid + i * TPB;
            const float* p = pb + (size_t)j * NCH;
            xp[j] = p[0]; yp[j] = p[1]; zp[j] = p[2];
        }
    }

    // Selected index 0 -> output row 0.
    if (m == 0 && tid < NCH) out[(size_t)b * KSEL * NCH + tid] = pb[tid];

    __syncthreads();   // drains vmcnt: prepass stores ordered before loads

    // Staging arrays: the compiler remats these loads into the k-loop and
    // streams coords from XCD-local L2 each round with deep vmcnt
    // batching (R12-proven pattern). COMPACT redirects the stream to the
    // planes: half the bytes, 4 lines/wave-instr instead of 24.
    float xr[PPT], yr[PPT], zr[PPT], dmin[PPT];
#pragma unroll
    for (int i = 0; i < PPT; ++i) {
        const int j = tid + i * TPB;
        if (COMPACT) {
            xr[i] = xp[base + j];
            yr[i] = yp[base + j];
            zr[i] = zp[base + j];
        } else {
            const float* p = pb + (size_t)(base + j) * NCH;
            xr[i] = p[0];
            yr[i] = p[1];
            zr[i] = p[2];
        }
        dmin[i] = __builtin_inff();
    }

    // p for round 1 is point 0 (uniform scalar loads of read-only data).
    float px = pb[0], py = pb[1], pz = pb[2];

    for (int k = 1; k < KSEL; ++k) {
        // ---- dist update + thread-local argmax (first-index tie-break) ----
        float bd = -1.0f;
        int   bj = 0;
#pragma unroll
        for (int i = 0; i < PPT; ++i) {
            // Bit-exact replication of the reference's f32 op sequence:
            // each op individually rounded (RN), no FMA / no reassociation.
            float dx = __fsub_rn(xr[i], px);
            float dy = __fsub_rn(yr[i], py);
            float dz = __fsub_rn(zr[i], pz);
            float d  = __fadd_rn(__fadd_rn(__fmul_rn(dx, dx),
                                           __fmul_rn(dy, dy)),
                                 __fmul_rn(dz, dz));
            float dm = dmin[i];
            dm = (d < dm) ? d : dm;
            dmin[i] = dm;
            // j = tid + i*TPB ascends with i: strict '>' keeps first index.
            if (dm > bd) { bd = dm; bj = tid + i * TPB; }
        }

        // ---- wave(64) argmax reduce, smaller index wins ties ----
        for (int off = 32; off > 0; off >>= 1) {
            float od = __shfl_down(bd, off);
            int   oj = __shfl_down(bj, off);
            if (od > bd || (od == bd && oj < bj)) { bd = od; bj = oj; }
        }
        if ((tid & 63) == 0) {
            const int w = tid >> 6;
            s_wd[w] = bd; s_wi[w] = bj;
        }
        __syncthreads();                                   // [A]

        unsigned long long* slot =
            pub + ((size_t)b * ROT + (size_t)(k & (ROT - 1))) * MBLK;

        // ---- publish this block's tagged key (tid 0) ----
        if (tid == 0) {
            float fd = s_wd[0]; int fi = s_wi[0];
#pragma unroll
            for (int w = 1; w < NWAVE; ++w) {
                if (s_wd[w] > fd || (s_wd[w] == fd && s_wi[w] < fi)) {
                    fd = s_wd[w]; fi = s_wi[w];
                }
            }
            const unsigned g   = (unsigned)(base + fi);
            const unsigned inv = 0xFFFFFu ^ g;             // 20-bit ~idx
            unsigned long long key =
                ((unsigned long long)__float_as_uint(fd) << 32)
                | ((unsigned long long)inv << 12)
                | (unsigned long long)(unsigned)k;         // 12-bit tag
            __hip_atomic_store(&slot[m], key, __ATOMIC_RELAXED,
                               __HIP_MEMORY_SCOPE_AGENT);
        }

        // ---- parallel poll: lane j waits for block j's word ----
        if (tid < MBLK) {
            unsigned long long v;
            do {
                v = __hip_atomic_load(&slot[tid], __ATOMIC_RELAXED,
                                      __HIP_MEMORY_SCOPE_AGENT);
            } while ((unsigned)(v & 0xFFFull) != (unsigned)k);
            s_key[tid] = v;
        }
        __syncthreads();                                   // [B]

        // ---- every thread: reduce 16 keys, fetch winner row (broadcast) ----
        // s_key reads precede next round's [A]; the poll rewrites s_key
        // only after [A] -> no race without a third barrier.
        unsigned long long mx = s_key[0];
#pragma unroll
        for (int w = 1; w < MBLK; ++w) {
            if (s_key[w] > mx) mx = s_key[w];
        }
        const unsigned g = 0xFFFFFu ^ (unsigned)((mx >> 12) & 0xFFFFFull);
        const float* pp = pb + (size_t)g * NCH;  // same addr all lanes: 1 txn
        px = pp[0]; py = pp[1]; pz = pp[2];

        // Round-robin writer block emits output row k.
        if ((k & (MBLK - 1)) == m && tid == 0) {
            float* o = out + ((size_t)b * KSEL + k) * NCH;
#pragma unroll
            for (int c = 0; c < NCH; ++c) o[c] = pp[c];
        }
    }
}

extern "C" void kernel_launch(void* const* d_in, const int* in_sizes, int n_in,
                              void* d_out, int out_size, void* d_ws, size_t ws_size,
                              hipStream_t stream) {
    const float* pts = (const float*)d_in[0];
    float* out = (float*)d_out;
    unsigned long long* pub = (unsigned long long*)d_ws;

    // pub[BATCH][ROT][MBLK] u64 = 4 KB; zero -> all tags 0 (never match).
    hipMemsetAsync(d_ws, 0,
                   (size_t)BATCH * ROT * MBLK * sizeof(unsigned long long),
                   stream);

    void* args[] = { (void*)&pts, (void*)&out, (void*)&pub };
    const void* fn = (ws_size >= WS_NEED)
        ? (const void*)fps_kernel<1>
        : (const void*)fps_kernel<0>;   // exact-R12 fallback if ws too small
    hipLaunchCooperativeKernel(fn, dim3(BATCH * MBLK), dim3(TPB),
                               args, 0, stream);
}